// Round 9
// baseline (432.259 us; speedup 1.0000x reference)
//
#include <hip/hip_runtime.h>
#include <hip/hip_bf16.h>

#define HH 64
#define TT 512
#define BB 16

typedef __attribute__((ext_vector_type(8))) short short8;
typedef __attribute__((ext_vector_type(4))) float f32x4;

#define K1 1.4426950408889634f   // log2(e)   — sigmoid-type pre-scale
#define K2 2.8853900817779268f   // 2*log2(e) — tanh-type pre-scale

static __device__ __forceinline__ unsigned short f2bf(float f) {
  unsigned u = __float_as_uint(f);
  u += 0x7fffu + ((u >> 16) & 1u);   // RNE (init-time packing only)
  return (unsigned short)(u >> 16);
}

static __device__ __forceinline__ short8 pack8s(const float* __restrict__ p, float s) {
  short8 r;
  #pragma unroll
  for (int i = 0; i < 8; ++i) r[i] = (short)f2bf(p[i] * s);
  return r;
}

static __device__ __forceinline__ f32x4 splat4(float b) {
  f32x4 r; r[0] = b; r[1] = b; r[2] = b; r[3] = b; return r;
}
static __device__ __forceinline__ f32x4 vexp4(f32x4 v) {
  f32x4 r;
  r[0] = __builtin_amdgcn_exp2f(v[0]); r[1] = __builtin_amdgcn_exp2f(v[1]);
  r[2] = __builtin_amdgcn_exp2f(v[2]); r[3] = __builtin_amdgcn_exp2f(v[3]);
  return r;
}
static __device__ __forceinline__ f32x4 vrcp4(f32x4 v) {
  f32x4 r;
  r[0] = __builtin_amdgcn_rcpf(v[0]); r[1] = __builtin_amdgcn_rcpf(v[1]);
  r[2] = __builtin_amdgcn_rcpf(v[2]); r[3] = __builtin_amdgcn_rcpf(v[3]);
  return r;
}
static __device__ __forceinline__ f32x4 vmin4(f32x4 a, float b) {
  return __builtin_elementwise_min(a, splat4(b));
}

// 7-trans LSTM cell update on FOUR hidden units (validated R6-R8).
// zi,zf,zo pre-scaled by K1; zg by K2; c in natural units.
static __device__ __forceinline__ f32x4 lstm_act4(f32x4 zi, f32x4 zf, f32x4 zg,
                                                  f32x4 zo, f32x4& c) {
  f32x4 Ei = vexp4(vmin4(zi, 16.f));       // upper clamp only
  f32x4 Ef = vexp4(vmin4(zf, 16.f));
  f32x4 G  = vexp4(vmin4(zg, 23.f));
  f32x4 Eo = vexp4(vmin4(zo, 16.f));
  f32x4 Pi = Ei + 1.f, Pf = Ef + 1.f, Pg = G + 1.f, Gm = G - 1.f;
  f32x4 t2 = Pi * Pg;
  f32x4 N  = Ef * c * t2 + Ei * Gm * Pf;
  f32x4 D  = Pf * t2;
  c = N * vrcp4(D);                         // c' = f*c + i*g
  f32x4 C2 = vexp4(vmin4(c * K2, 23.f));
  f32x4 num = Eo * (C2 - 1.f);
  f32x4 den = (Eo + 1.f) * (C2 + 1.f);
  return num * vrcp4(den);                  // h = o * tanh(c')
}

#define MF(A, B, C) __builtin_amdgcn_mfma_f32_16x16x32_bf16((A), (B), (C), 0, 0, 0)

// Merged step, phase P (compile-time). EVERY wave computes L0 step t (DO_A)
// and L1 step t-1 (DO_B) for its 16 gate-columns. Both L0 and L1 read
// h0buf[P^1]=h0(t-1); L1 also reads h1buf[P]=h1(t-2). Writes h0buf[P]=h0(t),
// h1buf[P^1]=h1(t-1). One basic block -> LLVM interleaves the independent
// MFMA/act chains (in-wave ILP replaces the 8-wave convoy).
#define STEP(P, DO_A, DO_B, LASTF) {                                           \
    const char* rd0 = (const char*)h0buf[(P) ^ 1];                             \
    const char* rd1 = (const char*)h1buf[P];                                   \
    short8 af0 = *(const short8*)(rd0 + rdo0);                                 \
    short8 af1 = *(const short8*)(rd0 + rdo1);                                 \
    if (DO_A) {                                                                \
      f32x4 xv = *(const f32x4*)xpf; xpf += BB;                                \
      f32x4 a0 = MF(af0, wfA[0], bsA[0]); a0 = MF(af1, wfA[1], a0);            \
      f32x4 a1 = MF(af0, wfA[2], bsA[1]); a1 = MF(af1, wfA[3], a1);            \
      f32x4 a2 = MF(af0, wfA[4], bsA[2]); a2 = MF(af1, wfA[5], a2);            \
      f32x4 a3 = MF(af0, wfA[6], bsA[3]); a3 = MF(af1, wfA[7], a3);            \
      a0 += xv * wxs[0]; a1 += xv * wxs[1];                                    \
      a2 += xv * wxs[2]; a3 += xv * wxs[3];                                    \
      f32x4 h4 = lstm_act4(a0, a1, a2, a3, cstA);                              \
      char* wrb = (char*)h0buf[P];                                             \
      *(__hip_bfloat16*)(wrb + wro[0]) = __float2bfloat16(h4[0]);              \
      *(__hip_bfloat16*)(wrb + wro[1]) = __float2bfloat16(h4[1]);              \
      *(__hip_bfloat16*)(wrb + wro[2]) = __float2bfloat16(h4[2]);              \
      *(__hip_bfloat16*)(wrb + wro[3]) = __float2bfloat16(h4[3]);              \
    }                                                                          \
    if (DO_B) {                                                                \
      short8 af2 = *(const short8*)(rd1 + rdo0);                               \
      short8 af3 = *(const short8*)(rd1 + rdo1);                               \
      f32x4 b0 = MF(af0, wfB[0],  bsB[0]); b0 = MF(af1, wfB[1],  b0);          \
      b0 = MF(af2, wfB[2],  b0);  b0 = MF(af3, wfB[3],  b0);                   \
      f32x4 b1 = MF(af0, wfB[4],  bsB[1]); b1 = MF(af1, wfB[5],  b1);          \
      b1 = MF(af2, wfB[6],  b1);  b1 = MF(af3, wfB[7],  b1);                   \
      f32x4 b2 = MF(af0, wfB[8],  bsB[2]); b2 = MF(af1, wfB[9],  b2);          \
      b2 = MF(af2, wfB[10], b2);  b2 = MF(af3, wfB[11], b2);                   \
      f32x4 b3 = MF(af0, wfB[12], bsB[3]); b3 = MF(af1, wfB[13], b3);          \
      b3 = MF(af2, wfB[14], b3);  b3 = MF(af3, wfB[15], b3);                   \
      f32x4 h4 = lstm_act4(b0, b1, b2, b3, cstB);                              \
      char* wrb = (char*)h1buf[(P) ^ 1];                                       \
      *(__hip_bfloat16*)(wrb + wro[0]) = __float2bfloat16(h4[0]);              \
      *(__hip_bfloat16*)(wrb + wro[1]) = __float2bfloat16(h4[1]);              \
      *(__hip_bfloat16*)(wrb + wro[2]) = __float2bfloat16(h4[2]);              \
      *(__hip_bfloat16*)(wrb + wro[3]) = __float2bfloat16(h4[3]);              \
      if (LASTF) {                                                             \
        h1f[(q * 4 + 0) * HH + colw] = h4[0];                                  \
        h1f[(q * 4 + 1) * HH + colw] = h4[1];                                  \
        h1f[(q * 4 + 2) * HH + colw] = h4[2];                                  \
        h1f[(q * 4 + 3) * HH + colw] = h4[3];                                  \
      }                                                                        \
    }                                                                          \
  }

__global__ __launch_bounds__(256, 1)
void lstm2_fused(const float* __restrict__ x,
                 const float* __restrict__ Wih0, const float* __restrict__ Whh0,
                 const float* __restrict__ bih0, const float* __restrict__ bhh0,
                 const float* __restrict__ Wih1, const float* __restrict__ Whh1,
                 const float* __restrict__ bih1, const float* __restrict__ bhh1,
                 const float* __restrict__ Wfc,  const float* __restrict__ bfc,
                 float* __restrict__ out)
{
  __shared__ float xs[TT * BB];                               // 32 KB, xs[t][row]
  __shared__ __align__(16) unsigned short h0buf[2][BB * HH];  // dbuf bf16, swizzled
  __shared__ __align__(16) unsigned short h1buf[2][BB * HH];
  __shared__ float h1f[BB * HH];                              // fp32 final h1

  const int tid  = threadIdx.x;
  const int wave = tid >> 6;       // 0..3: column-block (merged L0+L1 wave)
  const int lane = tid & 63;
  const int w    = wave;
  const int m    = lane & 15;
  const int q    = lane >> 4;
  const int b0   = blockIdx.x * BB;

  // ---- stage x transposed: xs[t][r] = x[b0+r][t] ----
  for (int t = tid; t < TT; t += 256) {
    #pragma unroll
    for (int r = 0; r < BB; ++r)
      xs[t * BB + r] = x[(size_t)(b0 + r) * TT + t];
  }
  // zero h state (bf16 zero == 0x0000): 2048 u32 total
  #pragma unroll
  for (int i = 0; i < 2; ++i) ((unsigned int*)h0buf)[tid + 256 * i * 2] = 0,
                              ((unsigned int*)h0buf)[tid + 256 * (i * 2 + 1)] = 0;
  #pragma unroll
  for (int i = 0; i < 4; ++i) ((unsigned int*)h1buf)[tid + 256 * i] = 0;

  // ---- pack PRE-SCALED weight B-fragments for BOTH layers (VGPR-resident) ----
  // wave w owns gate n-tiles {4n+w}: n=0->i,1->f,2->g,3->o, cols 16w..16w+15.
  // Scale K1 for i,f,o; K2 for g -> MFMA emits log2-domain pre-activations.
  short8 wfA[8], wfB[16];
  f32x4 bsA[4], bsB[4], wxs[4];
  #pragma unroll
  for (int n = 0; n < 4; ++n) {
    const float s = (n == 2) ? K2 : K1;
    const int colg = 16 * (4 * n + w) + m;
    bsA[n] = splat4((bih0[colg] + bhh0[colg]) * s);
    wxs[n] = splat4(Wih0[colg] * s);
    #pragma unroll
    for (int kt = 0; kt < 2; ++kt)
      wfA[n * 2 + kt] = pack8s(Whh0 + colg * HH + kt * 32 + q * 8, s);
    bsB[n] = splat4((bih1[colg] + bhh1[colg]) * s);
    #pragma unroll
    for (int kt = 0; kt < 4; ++kt) {     // kt 0,1: Wih1 (h0 input); kt 2,3: Whh1
      const float* Wsrc = (kt < 2) ? Wih1 : Whh1;
      wfB[n * 4 + kt] = pack8s(Wsrc + colg * HH + (kt & 1) * 32 + q * 8, s);
    }
  }

  // ---- loop-invariant LDS byte offsets (swizzle: 16B blocks XOR (row&7)<<4) ----
  const int colw = 16 * w + m;     // my h column within [0,64)
  const int rdo0 = m * 128 + ((q * 16) ^ ((m & 7) << 4));        // kt=0 A-frag
  const int rdo1 = m * 128 + ((64 + q * 16) ^ ((m & 7) << 4));   // kt=1 A-frag
  int wro[4];
  #pragma unroll
  for (int j = 0; j < 4; ++j) {
    const int row = q * 4 + j;
    wro[j] = row * 128 + ((2 * colw) ^ ((row & 7) << 4));
  }

  __syncthreads();   // x staged + h zeroed

  f32x4 cstA = splat4(0.f), cstB = splat4(0.f);
  const float* xpf = xs + q * 4;   // f32x4 covers batch rows 4q..4q+3

  // Iteration t (phase P = t&1): L0 step t (t<TT) + L1 step t-1 (t>=1),
  // both in EVERY wave. ONE barrier per step, 4-wave convoy.
  STEP(0, true, false, false)      // t=0 peel: L0 only
  __syncthreads();

  #pragma unroll 1
  for (int k = 0; k < (TT - 2) / 2; ++k) {   // t = 1..510
    STEP(1, true, true, false)
    __syncthreads();
    STEP(0, true, true, false)
    __syncthreads();
  }
  STEP(1, true, true, false)       // t=511: last L0 step + L1 step 510
  __syncthreads();
  STEP(0, false, true, true)       // t=512: L1 step 511 only, spill h1 to fp32
  __syncthreads();

  // ---- FC epilogue: out[b][o] = h1_final[b] . Wfc[o] + bfc[o] ----
  if (tid < BB * 7) {
    const int b = tid / 7, o = tid % 7;
    float s = bfc[o];
    #pragma unroll
    for (int k = 0; k < HH; ++k) s = fmaf(h1f[b * HH + k], Wfc[o * HH + k], s);
    out[(size_t)(b0 + b) * 7 + o] = s;
  }
}

extern "C" void kernel_launch(void* const* d_in, const int* in_sizes, int n_in,
                              void* d_out, int out_size, void* d_ws, size_t ws_size,
                              hipStream_t stream) {
  const float* x    = (const float*)d_in[0];
  const float* Wih0 = (const float*)d_in[1];
  const float* Whh0 = (const float*)d_in[2];
  const float* bih0 = (const float*)d_in[3];
  const float* bhh0 = (const float*)d_in[4];
  const float* Wih1 = (const float*)d_in[5];
  const float* Whh1 = (const float*)d_in[6];
  const float* bih1 = (const float*)d_in[7];
  const float* bhh1 = (const float*)d_in[8];
  const float* Wfc  = (const float*)d_in[9];
  const float* bfc  = (const float*)d_in[10];
  float* out = (float*)d_out;

  dim3 grid(4096 / BB);   // 256 workgroups, 1 per CU
  dim3 block(256);        // 4 merged waves (L0+L1 per wave), 1 barrier/step
  hipLaunchKernelGGL(lstm2_fused, grid, block, 0, stream,
                     x, Wih0, Whh0, bih0, bhh0, Wih1, Whh1, bih1, bhh1, Wfc, bfc, out);
}

// Round 10
// 369.006 us; speedup vs baseline: 1.1714x; 1.1714x over previous
//
#include <hip/hip_runtime.h>
#include <hip/hip_bf16.h>

#define HH 64
#define TT 512
#define BB 16

typedef __attribute__((ext_vector_type(8))) short short8;
typedef __attribute__((ext_vector_type(4))) float f32x4;
typedef __attribute__((ext_vector_type(2))) float f32x2;

#define K1 1.4426950408889634f   // log2(e)   — sigmoid-type pre-scale
#define K2 2.8853900817779268f   // 2*log2(e) — tanh-type pre-scale

static __device__ __forceinline__ unsigned short f2bf(float f) {
  unsigned u = __float_as_uint(f);
  u += 0x7fffu + ((u >> 16) & 1u);   // RNE (one-time weight pack only)
  return (unsigned short)(u >> 16);
}

static __device__ __forceinline__ short8 pack8s(const float* __restrict__ p, float s) {
  short8 r;
  #pragma unroll
  for (int i = 0; i < 8; ++i) r[i] = (short)f2bf(p[i] * s);
  return r;
}

static __device__ __forceinline__ f32x2 splat2(float b) { f32x2 r; r[0] = b; r[1] = b; return r; }
static __device__ __forceinline__ f32x2 vexp2(f32x2 v) {
  f32x2 r; r[0] = __builtin_amdgcn_exp2f(v[0]); r[1] = __builtin_amdgcn_exp2f(v[1]); return r;
}
static __device__ __forceinline__ f32x2 vrcp(f32x2 v) {
  f32x2 r; r[0] = __builtin_amdgcn_rcpf(v[0]); r[1] = __builtin_amdgcn_rcpf(v[1]); return r;
}
static __device__ __forceinline__ f32x2 vmin2(f32x2 a, float b) {
  return __builtin_elementwise_min(a, splat2(b));
}

// 7-trans LSTM cell update for a PAIR of hidden units (validated R6/R7:
// absmax identical to the 10-trans reference form).
// zi,zf,zo pre-scaled by K1; zg pre-scaled by K2; c in natural units.
// sigmoid(z)=E/(1+E) with E=e^z;  tanh(z)=(G-1)/(G+1) with G=e^{2z}.
static __device__ __forceinline__ f32x2 lstm_act2(f32x2 zi, f32x2 zf, f32x2 zg,
                                                  f32x2 zo, f32x2& c) {
  f32x2 Ei = vexp2(vmin2(zi, 16.f));       // upper clamp only: exp2(-big)->0 safe
  f32x2 Ef = vexp2(vmin2(zf, 16.f));
  f32x2 G  = vexp2(vmin2(zg, 23.f));
  f32x2 Eo = vexp2(vmin2(zo, 16.f));
  f32x2 Pi = Ei + 1.f, Pf = Ef + 1.f, Pg = G + 1.f, Gm = G - 1.f;
  f32x2 t2 = Pi * Pg;
  f32x2 N  = Ef * c * t2 + Ei * Gm * Pf;
  f32x2 D  = Pf * t2;
  c = N * vrcp(D);                          // c' = f*c + i*g  (exact mod fp32)
  f32x2 C2 = vexp2(vmin2(c * K2, 23.f));
  f32x2 num = Eo * (C2 - 1.f);
  f32x2 den = (Eo + 1.f) * (C2 + 1.f);
  return num * vrcp(den);                   // h = o * tanh(c')
}

#define MF(A, B, C) __builtin_amdgcn_mfma_f32_16x16x32_bf16((A), (B), (C), 0, 0, 0)

// ---- one LSTM-layer-0 step, phase P (compile-time). Reads h0buf[P^1], writes h0buf[P].
#define STEP_A(P) {                                                            \
    const char* rd = (const char*)h0buf[(P) ^ 1];                              \
    short8 af0 = *(const short8*)(rd + rdo0);                                  \
    short8 af1 = *(const short8*)(rd + rdo1);                                  \
    f32x4 xv = *(const f32x4*)xpf; xpf += BB;                                  \
    f32x4 a0 = MF(af0, wf[0], bs[0]); a0 = MF(af1, wf[1], a0);                 \
    f32x4 a1 = MF(af0, wf[2], bs[1]); a1 = MF(af1, wf[3], a1);                 \
    f32x4 a2 = MF(af0, wf[4], bs[2]); a2 = MF(af1, wf[5], a2);                 \
    f32x4 a3 = MF(af0, wf[6], bs[3]); a3 = MF(af1, wf[7], a3);                 \
    char* wrb = (char*)h0buf[P];                                               \
    {                                                                          \
      f32x2 xp2 = {xv[0], xv[1]};                                              \
      f32x2 zi = {a0[0], a0[1]}; zi += xp2 * wxs[0];                           \
      f32x2 zf = {a1[0], a1[1]}; zf += xp2 * wxs[1];                           \
      f32x2 zg = {a2[0], a2[1]}; zg += xp2 * wxs[2];                           \
      f32x2 zo = {a3[0], a3[1]}; zo += xp2 * wxs[3];                           \
      f32x2 h2 = lstm_act2(zi, zf, zg, zo, cst01);                             \
      *(__hip_bfloat16*)(wrb + wro[0]) = __float2bfloat16(h2[0]);              \
      *(__hip_bfloat16*)(wrb + wro[1]) = __float2bfloat16(h2[1]);              \
    }                                                                          \
    {                                                                          \
      f32x2 xp2 = {xv[2], xv[3]};                                              \
      f32x2 zi = {a0[2], a0[3]}; zi += xp2 * wxs[0];                           \
      f32x2 zf = {a1[2], a1[3]}; zf += xp2 * wxs[1];                           \
      f32x2 zg = {a2[2], a2[3]}; zg += xp2 * wxs[2];                           \
      f32x2 zo = {a3[2], a3[3]}; zo += xp2 * wxs[3];                           \
      f32x2 h2 = lstm_act2(zi, zf, zg, zo, cst23);                             \
      *(__hip_bfloat16*)(wrb + wro[2]) = __float2bfloat16(h2[0]);              \
      *(__hip_bfloat16*)(wrb + wro[3]) = __float2bfloat16(h2[1]);              \
    }                                                                          \
  }

// ---- one LSTM-layer-1 step, phase P. Reads h0buf[P^1] (input) + h1buf[P]
// (recurrent, 2 steps old), writes h1buf[P^1].
#define STEP_B(P, LAST) {                                                      \
    const char* rd0 = (const char*)h0buf[(P) ^ 1];                             \
    const char* rd1 = (const char*)h1buf[P];                                   \
    short8 af0 = *(const short8*)(rd0 + rdo0);                                 \
    short8 af1 = *(const short8*)(rd0 + rdo1);                                 \
    short8 af2 = *(const short8*)(rd1 + rdo0);                                 \
    short8 af3 = *(const short8*)(rd1 + rdo1);                                 \
    f32x4 a0 = MF(af0, wf[0],  bs[0]); a0 = MF(af1, wf[1],  a0);               \
    a0 = MF(af2, wf[2],  a0);  a0 = MF(af3, wf[3],  a0);                       \
    f32x4 a1 = MF(af0, wf[4],  bs[1]); a1 = MF(af1, wf[5],  a1);               \
    a1 = MF(af2, wf[6],  a1);  a1 = MF(af3, wf[7],  a1);                       \
    f32x4 a2 = MF(af0, wf[8],  bs[2]); a2 = MF(af1, wf[9],  a2);               \
    a2 = MF(af2, wf[10], a2);  a2 = MF(af3, wf[11], a2);                       \
    f32x4 a3 = MF(af0, wf[12], bs[3]); a3 = MF(af1, wf[13], a3);               \
    a3 = MF(af2, wf[14], a3);  a3 = MF(af3, wf[15], a3);                       \
    char* wrb = (char*)h1buf[(P) ^ 1];                                         \
    {                                                                          \
      f32x2 zi = {a0[0], a0[1]}, zf = {a1[0], a1[1]};                          \
      f32x2 zg = {a2[0], a2[1]}, zo = {a3[0], a3[1]};                          \
      f32x2 h2 = lstm_act2(zi, zf, zg, zo, cst01);                             \
      *(__hip_bfloat16*)(wrb + wro[0]) = __float2bfloat16(h2[0]);              \
      *(__hip_bfloat16*)(wrb + wro[1]) = __float2bfloat16(h2[1]);              \
      if (LAST) {                                                              \
        h1f[(q * 4 + 0) * HH + colw] = h2[0];                                  \
        h1f[(q * 4 + 1) * HH + colw] = h2[1];                                  \
      }                                                                        \
    }                                                                          \
    {                                                                          \
      f32x2 zi = {a0[2], a0[3]}, zf = {a1[2], a1[3]};                          \
      f32x2 zg = {a2[2], a2[3]}, zo = {a3[2], a3[3]};                          \
      f32x2 h2 = lstm_act2(zi, zf, zg, zo, cst23);                             \
      *(__hip_bfloat16*)(wrb + wro[2]) = __float2bfloat16(h2[0]);              \
      *(__hip_bfloat16*)(wrb + wro[3]) = __float2bfloat16(h2[1]);              \
      if (LAST) {                                                              \
        h1f[(q * 4 + 2) * HH + colw] = h2[0];                                  \
        h1f[(q * 4 + 3) * HH + colw] = h2[1];                                  \
      }                                                                        \
    }                                                                          \
  }

__global__ __launch_bounds__(512, 2)
void lstm2_fused(const float* __restrict__ x,
                 const float* __restrict__ Wih0, const float* __restrict__ Whh0,
                 const float* __restrict__ bih0, const float* __restrict__ bhh0,
                 const float* __restrict__ Wih1, const float* __restrict__ Whh1,
                 const float* __restrict__ bih1, const float* __restrict__ bhh1,
                 const float* __restrict__ Wfc,  const float* __restrict__ bfc,
                 float* __restrict__ out)
{
  __shared__ float xs[TT * BB];                               // 32 KB, xs[t][row]
  __shared__ __align__(16) unsigned short h0buf[2][BB * HH];  // dbuf bf16, swizzled
  __shared__ __align__(16) unsigned short h1buf[2][BB * HH];
  __shared__ float h1f[BB * HH];                              // fp32 final h1

  const int tid  = threadIdx.x;
  const int wave = tid >> 6;
  const int lane = tid & 63;
  const int grp  = wave >> 2;      // 0: layer0 (4 waves), 1: layer1 (4 waves)
  const int w    = wave & 3;       // column-block 0..3
  const int m    = lane & 15;
  const int q    = lane >> 4;
  const int b0   = blockIdx.x * BB;

  // ---- stage x transposed: xs[t][r] = x[b0+r][t] ----
  {
    const int t = tid;             // blockDim.x == 512 == TT
    #pragma unroll
    for (int r = 0; r < BB; ++r)
      xs[t * BB + r] = x[(size_t)(b0 + r) * TT + t];
  }
  // zero h state (bf16 zero == 0x0000): each buf = 1024 uints
  ((unsigned int*)h0buf)[tid] = 0; ((unsigned int*)h0buf)[tid + 512] = 0;
  ((unsigned int*)h1buf)[tid] = 0; ((unsigned int*)h1buf)[tid + 512] = 0;

  // ---- pack PRE-SCALED weight B-fragments (held in VGPRs the whole loop) ----
  // wave w owns gate n-tiles {4n+w}: n=0->i,1->f,2->g,3->o, cols 16w..16w+15.
  // Scale K1 for i,f,o; K2 for g -> MFMA emits log2-domain pre-activations.
  short8 wf[16];
  f32x4 bs[4];
  f32x2 wxs[4];
  #pragma unroll
  for (int n = 0; n < 4; ++n) {
    const float s = (n == 2) ? K2 : K1;
    const int colg = 16 * (4 * n + w) + m;
    if (grp == 0) {
      const float b = (bih0[colg] + bhh0[colg]) * s;
      bs[n][0] = b; bs[n][1] = b; bs[n][2] = b; bs[n][3] = b;
      wxs[n] = splat2(Wih0[colg] * s);
      #pragma unroll
      for (int kt = 0; kt < 2; ++kt)
        wf[n * 2 + kt] = pack8s(Whh0 + colg * HH + kt * 32 + q * 8, s);
    } else {
      const float b = (bih1[colg] + bhh1[colg]) * s;
      bs[n][0] = b; bs[n][1] = b; bs[n][2] = b; bs[n][3] = b;
      wxs[n] = splat2(0.f);
      #pragma unroll
      for (int kt = 0; kt < 4; ++kt) {   // kt 0,1: Wih1 (h0 input); kt 2,3: Whh1
        const float* Wsrc = (kt < 2) ? Wih1 : Whh1;
        wf[n * 4 + kt] = pack8s(Wsrc + colg * HH + (kt & 1) * 32 + q * 8, s);
      }
    }
  }

  // ---- loop-invariant LDS byte offsets (swizzle: 16B blocks XOR (row&7)<<4) ----
  const int colw = 16 * w + m;     // my h column within [0,64)
  const int rdo0 = m * 128 + ((q * 16) ^ ((m & 7) << 4));        // kt=0 A-frag
  const int rdo1 = m * 128 + ((64 + q * 16) ^ ((m & 7) << 4));   // kt=1 A-frag
  int wro[4];
  #pragma unroll
  for (int j = 0; j < 4; ++j) {
    const int row = q * 4 + j;
    wro[j] = row * 128 + ((2 * colw) ^ ((row & 7) << 4));
  }

  __syncthreads();   // x staged + h zeroed

  f32x2 cst01 = splat2(0.f), cst23 = splat2(0.f);
  const float* xpf = xs + q * 4;   // advances 16 floats per layer-0 step

  // Iteration t (phase P = t&1): A computes L0 step t (t<TT);
  // B computes L1 step t-1 (t>=1). ONE barrier per step.
  if (grp == 0) { STEP_A(0) }      // t=0 peel
  __syncthreads();

  #pragma unroll 1
  for (int k = 0; k < (TT - 2) / 2; ++k) {   // t = 1..510
    if (grp == 0) { STEP_A(1) } else { STEP_B(1, false) }
    __syncthreads();
    if (grp == 0) { STEP_A(0) } else { STEP_B(0, false) }
    __syncthreads();
  }
  // t=511 (P=1): both.
  if (grp == 0) { STEP_A(1) } else { STEP_B(1, false) }
  __syncthreads();
  // t=512 (P=0): B only, final h1 spilled to fp32.
  if (grp == 1) { STEP_B(0, true) }
  __syncthreads();

  // ---- FC epilogue: out[b][o] = h1_final[b] . Wfc[o] + bfc[o] ----
  if (tid < BB * 7) {
    const int b = tid / 7, o = tid % 7;
    float s = bfc[o];
    #pragma unroll
    for (int k = 0; k < HH; ++k) s = fmaf(h1f[b * HH + k], Wfc[o * HH + k], s);
    out[(size_t)(b0 + b) * 7 + o] = s;
  }
}

extern "C" void kernel_launch(void* const* d_in, const int* in_sizes, int n_in,
                              void* d_out, int out_size, void* d_ws, size_t ws_size,
                              hipStream_t stream) {
  const float* x    = (const float*)d_in[0];
  const float* Wih0 = (const float*)d_in[1];
  const float* Whh0 = (const float*)d_in[2];
  const float* bih0 = (const float*)d_in[3];
  const float* bhh0 = (const float*)d_in[4];
  const float* Wih1 = (const float*)d_in[5];
  const float* Whh1 = (const float*)d_in[6];
  const float* bih1 = (const float*)d_in[7];
  const float* bhh1 = (const float*)d_in[8];
  const float* Wfc  = (const float*)d_in[9];
  const float* bfc  = (const float*)d_in[10];
  float* out = (float*)d_out;

  dim3 grid(4096 / BB);   // 256 workgroups, 1 per CU
  dim3 block(512);        // 8 waves: 4 layer-0 + 4 layer-1, pipelined
  hipLaunchKernelGGL(lstm2_fused, grid, block, 0, stream,
                     x, Wih0, Whh0, bih0, bhh0, Wih1, Whh1, bih1, bhh1, Wfc, bfc, out);
}